// Round 1
// baseline (1270.384 us; speedup 1.0000x reference)
//
#include <hip/hip_runtime.h>
#include <hip/hip_fp16.h>
#include <math.h>

#define N_B 16
#define N_A 1024
#define N_D 1024
#define N_H 512
#define N_W 512

// ---------------------------------------------------------------------------
// Setup: twiddle table W[k] = exp(-2*pi*i*k/1024), k<512 (double precision),
// and per-angle (cos, sin) table (double precision).
// ---------------------------------------------------------------------------
__global__ void fan_setup_kernel(const float* __restrict__ angles,
                                 float* __restrict__ twr,
                                 float* __restrict__ twi,
                                 float2* __restrict__ cs) {
    int t = blockIdx.x * 256 + threadIdx.x;
    if (t < 512) {
        double ang = -2.0 * M_PI * (double)t / 1024.0;
        twr[t] = (float)cos(ang);
        twi[t] = (float)sin(ang);
    }
    if (t < 1024) {
        double b = (double)angles[t];
        cs[t] = make_float2((float)cos(b), (float)sin(b));
    }
}

// ---------------------------------------------------------------------------
// FFT ramp filter. One block = one PAIR of real rows packed as complex.
// Forward radix-2 DIF (natural->bitrev), multiply by filt[bitrev(i)],
// inverse radix-2 DIT (bitrev->natural), scale by 1/N.
// Output: packed half2 (f[i], f[i+1]) for single-gather bilinear sampling.
// ---------------------------------------------------------------------------
__global__ __launch_bounds__(256) void fan_fft_filter_kernel(
    const float* __restrict__ sino, const float* __restrict__ filt,
    const float* __restrict__ twr_g, const float* __restrict__ twi_g,
    __half2* __restrict__ pf) {
    __shared__ float s_re[1024];
    __shared__ float s_im[1024];
    __shared__ float s_twr[512];
    __shared__ float s_twi[512];

    const int tid = threadIdx.x;
    const int m0 = blockIdx.x * 2;
    const int m1 = m0 + 1;

    // load twiddles
    {
        float2 a = ((const float2*)twr_g)[tid];
        s_twr[2 * tid] = a.x; s_twr[2 * tid + 1] = a.y;
        float2 b = ((const float2*)twi_g)[tid];
        s_twi[2 * tid] = b.x; s_twi[2 * tid + 1] = b.y;
    }
    // load the two rows (coalesced float4)
    {
        const float4* r0 = (const float4*)(sino + (size_t)m0 * N_D);
        const float4* r1 = (const float4*)(sino + (size_t)m1 * N_D);
        ((float4*)s_re)[tid] = r0[tid];
        ((float4*)s_im)[tid] = r1[tid];
    }
    __syncthreads();

    // ---- forward DIF: natural in -> bit-reversed out ----
    for (int L = 9; L >= 0; --L) {
        const int half = 1 << L;
#pragma unroll
        for (int q = 0; q < 2; ++q) {
            const int bf = tid + (q << 8);
            const int j = bf & (half - 1);
            const int blk = bf >> L;
            const int base = (blk << (L + 1)) + j;
            const int tw = j << (9 - L);
            const float wr = s_twr[tw], wi = s_twi[tw];
            const float ar = s_re[base], ai = s_im[base];
            const float br = s_re[base + half], bi = s_im[base + half];
            s_re[base] = ar + br;
            s_im[base] = ai + bi;
            const float dr = ar - br, di = ai - bi;
            s_re[base + half] = dr * wr - di * wi;
            s_im[base + half] = dr * wi + di * wr;
        }
        __syncthreads();
    }

    // ---- multiply by real ramp filter (bit-reversed order) ----
#pragma unroll
    for (int q = 0; q < 4; ++q) {
        const int i = tid + (q << 8);
        const int ri = (int)(__brev((unsigned)i) >> 22);
        const float f = filt[ri];
        s_re[i] *= f;
        s_im[i] *= f;
    }
    __syncthreads();

    // ---- inverse DIT: bit-reversed in -> natural out (unnormalized) ----
    for (int L = 0; L <= 9; ++L) {
        const int half = 1 << L;
#pragma unroll
        for (int q = 0; q < 2; ++q) {
            const int bf = tid + (q << 8);
            const int j = bf & (half - 1);
            const int blk = bf >> L;
            const int base = (blk << (L + 1)) + j;
            const int tw = j << (9 - L);
            const float wr = s_twr[tw], wi = -s_twi[tw];
            const float ar = s_re[base], ai = s_im[base];
            const float tr = s_re[base + half], ti = s_im[base + half];
            const float br = tr * wr - ti * wi;
            const float bi = tr * wi + ti * wr;
            s_re[base] = ar + br;
            s_im[base] = ai + bi;
            s_re[base + half] = ar - br;
            s_im[base + half] = ai - bi;
        }
        __syncthreads();
    }

    // ---- scale by 1/N and store packed (f[i], f[i+1]) as half2 ----
    const float invN = 1.0f / 1024.0f;
#pragma unroll
    for (int q = 0; q < 4; ++q) {
        const int n = tid + (q << 8);
        const float a0 = s_re[n] * invN;
        const float a1 = (n < 1023) ? s_re[n + 1] * invN : 0.0f;
        pf[(size_t)m0 * N_D + n] = __floats2half2_rn(a0, a1);
        const float b0 = s_im[n] * invN;
        const float b1 = (n < 1023) ? s_im[n + 1] * invN : 0.0f;
        pf[(size_t)m1 * N_D + n] = __floats2half2_rn(b0, b1);
    }
}

// ---------------------------------------------------------------------------
// Backprojection: thread per pixel, 16 batch accumulators, 1024-angle loop.
// ---------------------------------------------------------------------------
__global__ __launch_bounds__(256) void fan_backproject_kernel(
    const __half2* __restrict__ pf, const float2* __restrict__ cs_g,
    float* __restrict__ out) {
    __shared__ float2 lcs[1024];
    const int tid = threadIdx.x;
#pragma unroll
    for (int q = 0; q < 4; ++q) {
        const int a = tid + (q << 8);
        lcs[a] = cs_g[a];
    }
    __syncthreads();

    const int p = blockIdx.x * 256 + tid;
    const int xi = p & (N_W - 1);
    const int yi = p >> 9;
    const float x = ((float)xi - 255.5f);  // VX = 1.0
    const float y = ((float)yi - 255.5f);

    float acc[N_B];
#pragma unroll
    for (int b = 0; b < N_B; ++b) acc[b] = 0.0f;

    for (int a = 0; a < N_A; ++a) {
        const float2 csp = lcs[a];
        const float c = csp.x, s = csp.y;
        const float t = 750.0f + x * c + y * s;       // D_SI + X c + Y s
        // reciprocal: hw rcp + 1 Newton step
        float r = __builtin_amdgcn_rcpf(t);
        r = r * (2.0f - t * r);
        const float num = y * c - x * s;
        const float u = 1200.0f * num * r;            // D_SD * (...) / t
        const float idx = u * 0.8f + 511.5f;          // u/DU + (D-1)/2, DU=1.25
        float i0f = floorf(idx);
        i0f = fminf(fmaxf(i0f, 0.0f), 1022.0f);
        float frac = idx - i0f;
        frac = fminf(fmaxf(frac, 0.0f), 1.0f);
        float wd = 750.0f * r;
        wd = wd * wd;                                 // (D_SI/t)^2
        const bool inside = (idx >= 0.0f) && (idx <= 1023.0f);
        wd = inside ? wd : 0.0f;
        const float w1 = wd * frac;
        const float w0 = wd - w1;
        const unsigned off = ((unsigned)a << 10) + (unsigned)(int)i0f;
#pragma unroll
        for (int b = 0; b < N_B; ++b) {
            const __half2 h = pf[off + (unsigned)b * (N_A * N_D)];
            const float v0 = __low2float(h);
            const float v1 = __high2float(h);
            acc[b] = fmaf(v1, w1, fmaf(v0, w0, acc[b]));
        }
    }

    const float scale = 3.14159265358979323846f / 1024.0f;  // pi / A
#pragma unroll
    for (int b = 0; b < N_B; ++b) {
        out[(size_t)b * (N_H * N_W) + (size_t)p] = acc[b] * scale;
    }
}

// ---------------------------------------------------------------------------
extern "C" void kernel_launch(void* const* d_in, const int* in_sizes, int n_in,
                              void* d_out, int out_size, void* d_ws, size_t ws_size,
                              hipStream_t stream) {
    const float* sino = (const float*)d_in[0];    // [16, 1024, 1024] f32
    const float* filt = (const float*)d_in[1];    // [1024] f32
    const float* angles = (const float*)d_in[2];  // [1024] f32
    float* out = (float*)d_out;                   // [16, 512, 512] f32

    // workspace layout (floats): twr[512] | twi[512] | cs[1024 float2] | pad | pf
    float* twr = (float*)d_ws;
    float* twi = twr + 512;
    float2* cs = (float2*)(twi + 512);
    __half2* pf = (__half2*)((char*)d_ws + 16384);  // 16 MiW = 64 MB of half2

    fan_setup_kernel<<<4, 256, 0, stream>>>(angles, twr, twi, cs);
    fan_fft_filter_kernel<<<(N_B * N_A) / 2, 256, 0, stream>>>(sino, filt, twr, twi, pf);
    fan_backproject_kernel<<<(N_H * N_W) / 256, 256, 0, stream>>>(pf, cs, out);
}

// Round 3
// 1190.162 us; speedup vs baseline: 1.0674x; 1.0674x over previous
//
#include <hip/hip_runtime.h>
#include <hip/hip_fp16.h>
#include <math.h>

#define N_B 16
#define N_A 1024
#define N_D 1024
#define N_H 512
#define N_W 512

typedef _Float16 half2t __attribute__((ext_vector_type(2)));

__device__ inline half2t h2cast(unsigned u) {
    union { unsigned u; half2t h; } cv; cv.u = u; return cv.h;
}

__device__ inline float fdot2f(half2t a, half2t b, float c) {
#if __has_builtin(__builtin_amdgcn_fdot2)
    return __builtin_amdgcn_fdot2(a, b, c, false);
#else
    asm("v_dot2_f32_f16 %0, %1, %2, %0" : "+v"(c) : "v"(a), "v"(b));
    return c;
#endif
}

__device__ inline half2t pack_h2(float lo, float hi) {
#if __has_builtin(__builtin_amdgcn_cvt_pkrtz)
    auto r = __builtin_amdgcn_cvt_pkrtz(lo, hi);
    union { decltype(r) a; half2t h; } cv; cv.a = r; return cv.h;
#else
    half2t r; r.x = (_Float16)lo; r.y = (_Float16)hi; return r;
#endif
}

// ---------------------------------------------------------------------------
// Setup: twiddle table W[k] = exp(-2*pi*i*k/1024), k<512 (double precision),
// and per-angle (cos, sin) table (double precision).
// ---------------------------------------------------------------------------
__global__ void fan_setup_kernel(const float* __restrict__ angles,
                                 float* __restrict__ twr,
                                 float* __restrict__ twi,
                                 float2* __restrict__ cs) {
    int t = blockIdx.x * 256 + threadIdx.x;
    if (t < 512) {
        double ang = -2.0 * M_PI * (double)t / 1024.0;
        twr[t] = (float)cos(ang);
        twi[t] = (float)sin(ang);
    }
    if (t < 1024) {
        double b = (double)angles[t];
        cs[t] = make_float2((float)cos(b), (float)sin(b));
    }
}

// ---------------------------------------------------------------------------
// FFT ramp filter. One block = one PAIR of real rows packed as complex.
// Forward radix-2 DIF (natural->bitrev), multiply by filt[bitrev(i)],
// inverse radix-2 DIT (bitrev->natural), scale by 1/N.
// Output layout [b][a][d]: packed half2 (f[d], f[d+1]) for single-gather
// bilinear sampling (adjacent lanes -> adjacent bytes -> good coalescing).
// ---------------------------------------------------------------------------
__global__ __launch_bounds__(256) void fan_fft_filter_kernel(
    const float* __restrict__ sino, const float* __restrict__ filt,
    const float* __restrict__ twr_g, const float* __restrict__ twi_g,
    __half2* __restrict__ pf) {
    __shared__ float s_re[1024];
    __shared__ float s_im[1024];
    __shared__ float s_twr[512];
    __shared__ float s_twi[512];

    const int tid = threadIdx.x;
    const int m0 = blockIdx.x * 2;
    const int m1 = m0 + 1;

    {
        float2 a = ((const float2*)twr_g)[tid];
        s_twr[2 * tid] = a.x; s_twr[2 * tid + 1] = a.y;
        float2 b = ((const float2*)twi_g)[tid];
        s_twi[2 * tid] = b.x; s_twi[2 * tid + 1] = b.y;
    }
    {
        const float4* r0 = (const float4*)(sino + (size_t)m0 * N_D);
        const float4* r1 = (const float4*)(sino + (size_t)m1 * N_D);
        ((float4*)s_re)[tid] = r0[tid];
        ((float4*)s_im)[tid] = r1[tid];
    }
    __syncthreads();

    // ---- forward DIF: natural in -> bit-reversed out ----
    for (int L = 9; L >= 0; --L) {
        const int half = 1 << L;
#pragma unroll
        for (int q = 0; q < 2; ++q) {
            const int bf = tid + (q << 8);
            const int j = bf & (half - 1);
            const int blk = bf >> L;
            const int base = (blk << (L + 1)) + j;
            const int tw = j << (9 - L);
            const float wr = s_twr[tw], wi = s_twi[tw];
            const float ar = s_re[base], ai = s_im[base];
            const float br = s_re[base + half], bi = s_im[base + half];
            s_re[base] = ar + br;
            s_im[base] = ai + bi;
            const float dr = ar - br, di = ai - bi;
            s_re[base + half] = dr * wr - di * wi;
            s_im[base + half] = dr * wi + di * wr;
        }
        __syncthreads();
    }

    // ---- multiply by real ramp filter (bit-reversed order) ----
#pragma unroll
    for (int q = 0; q < 4; ++q) {
        const int i = tid + (q << 8);
        const int ri = (int)(__brev((unsigned)i) >> 22);
        const float f = filt[ri];
        s_re[i] *= f;
        s_im[i] *= f;
    }
    __syncthreads();

    // ---- inverse DIT: bit-reversed in -> natural out (unnormalized) ----
    for (int L = 0; L <= 9; ++L) {
        const int half = 1 << L;
#pragma unroll
        for (int q = 0; q < 2; ++q) {
            const int bf = tid + (q << 8);
            const int j = bf & (half - 1);
            const int blk = bf >> L;
            const int base = (blk << (L + 1)) + j;
            const int tw = j << (9 - L);
            const float wr = s_twr[tw], wi = -s_twi[tw];
            const float ar = s_re[base], ai = s_im[base];
            const float tr = s_re[base + half], ti = s_im[base + half];
            const float br = tr * wr - ti * wi;
            const float bi = tr * wi + ti * wr;
            s_re[base] = ar + br;
            s_im[base] = ai + bi;
            s_re[base + half] = ar - br;
            s_im[base + half] = ai - bi;
        }
        __syncthreads();
    }

    // ---- scale by 1/N, store packed (f[i], f[i+1]) as half2, [b][a][d] ----
    const float invN = 1.0f / 1024.0f;
#pragma unroll
    for (int q = 0; q < 4; ++q) {
        const int n = tid + (q << 8);
        const float a0 = s_re[n] * invN;
        const float a1 = (n < 1023) ? s_re[n + 1] * invN : 0.0f;
        pf[(size_t)m0 * N_D + n] = __floats2half2_rn(a0, a1);
        const float b0 = s_im[n] * invN;
        const float b1 = (n < 1023) ? s_im[n + 1] * invN : 0.0f;
        pf[(size_t)m1 * N_D + n] = __floats2half2_rn(b0, b1);
    }
}

// ---------------------------------------------------------------------------
// Backprojection: thread per pixel, 16 batch accumulators, angle loop.
// SPLIT=2: blockIdx parity selects angle half; partial sums, reduced after.
// Per-batch base pointers are wave-uniform -> SGPR-pair saddr form; one
// 32-bit voffset per angle shared by all 16 loads. v_dot2_f32_f16 does the
// bilinear (v0*w0 + v1*w1) in one instruction per batch.
// ---------------------------------------------------------------------------
template <int SPLIT>
__global__ __launch_bounds__(256) void fan_backproject_kernel(
    const unsigned* __restrict__ pfu, const float2* __restrict__ cs_g,
    float* __restrict__ dst0, float* __restrict__ dst1) {
    __shared__ float2 lcs[N_A];
    const int tid = threadIdx.x;
#pragma unroll
    for (int q = 0; q < 4; ++q) {
        const int a = tid + (q << 8);
        lcs[a] = cs_g[a];
    }
    __syncthreads();

    const int part = (SPLIT == 2) ? (blockIdx.x & 1) : 0;
    const int pb = (SPLIT == 2) ? (blockIdx.x >> 1) : blockIdx.x;
    const int ACNT = N_A / SPLIT;
    const int abase = part * ACNT;

    const int p = pb * 256 + tid;
    const int xi = p & (N_W - 1);
    const int yi = p >> 9;
    const float x = ((float)xi - 255.5f);  // VX = 1.0
    const float y = ((float)yi - 255.5f);

    float acc[N_B];
#pragma unroll
    for (int b = 0; b < N_B; ++b) acc[b] = 0.0f;

    for (int aa = 0; aa < ACNT; ++aa) {
        const int a = abase + aa;
        const float2 csp = lcs[a];
        const float c = csp.x, s = csp.y;
        const float t = fmaf(x, c, fmaf(y, s, 750.0f));  // D_SI + X c + Y s
        float r = __builtin_amdgcn_rcpf(t);
        r = r * (2.0f - t * r);                          // 1 Newton step
        const float num = fmaf(y, c, -(x * s));
        const float idx = fmaf(num * r, 960.0f, 511.5f); // D_SD/DU=960
        float i0f = floorf(idx);
        i0f = fminf(fmaxf(i0f, 0.0f), 1022.0f);
        const float frac = fminf(fmaxf(idx - i0f, 0.0f), 1.0f);
        float wd = 750.0f * r;
        wd = wd * wd;                                    // (D_SI/t)^2
        wd = (idx >= 0.0f && idx <= 1023.0f) ? wd : 0.0f;
        const float w1 = wd * frac;
        const float w0 = wd - w1;
        const half2t wp = pack_h2(w0, w1);
        const unsigned off = ((unsigned)a << 10) + (unsigned)(int)i0f;
#pragma unroll
        for (int b = 0; b < N_B; ++b) {
            const unsigned v = (pfu + (size_t)b * (N_A * N_D))[off];
            acc[b] = fdot2f(h2cast(v), wp, acc[b]);
        }
    }

    const float scale = 3.14159265358979323846f / 1024.0f;  // pi / A
    float* dst = (SPLIT == 2 && part == 1) ? dst1 : dst0;
#pragma unroll
    for (int b = 0; b < N_B; ++b) {
        dst[(size_t)b * (N_H * N_W) + (size_t)p] = acc[b] * scale;
    }
}

// ---------------------------------------------------------------------------
__global__ __launch_bounds__(256) void fan_reduce_kernel(
    const float4* __restrict__ a, const float4* __restrict__ b,
    float4* __restrict__ o) {
    const int i = blockIdx.x * 256 + threadIdx.x;
    const float4 va = a[i], vb = b[i];
    o[i] = make_float4(va.x + vb.x, va.y + vb.y, va.z + vb.z, va.w + vb.w);
}

// ---------------------------------------------------------------------------
extern "C" void kernel_launch(void* const* d_in, const int* in_sizes, int n_in,
                              void* d_out, int out_size, void* d_ws, size_t ws_size,
                              hipStream_t stream) {
    const float* sino = (const float*)d_in[0];    // [16, 1024, 1024] f32
    const float* filt = (const float*)d_in[1];    // [1024] f32
    const float* angles = (const float*)d_in[2];  // [1024] f32
    float* out = (float*)d_out;                   // [16, 512, 512] f32

    // ws layout: twr[512]f | twi[512]f | cs[1024]f2 | pad to 16KB |
    //            pf (64MB half2, [b][a][d] pair-packed) | partial0/1 (16MB ea)
    float* twr = (float*)d_ws;
    float* twi = twr + 512;
    float2* cs = (float2*)(twi + 512);
    char* base = (char*)d_ws;
    __half2* pf = (__half2*)(base + 16384);
    const size_t PF_BYTES = (size_t)N_B * N_A * N_D * 4;  // 64 MB
    float* partial0 = (float*)(base + 16384 + PF_BYTES);
    float* partial1 = partial0 + (size_t)N_B * N_H * N_W;
    const size_t need = 16384 + PF_BYTES + 2 * (size_t)N_B * N_H * N_W * 4;

    fan_setup_kernel<<<4, 256, 0, stream>>>(angles, twr, twi, cs);
    fan_fft_filter_kernel<<<(N_B * N_A) / 2, 256, 0, stream>>>(sino, filt, twr,
                                                               twi, pf);
    if (ws_size >= need) {
        fan_backproject_kernel<2><<<(N_H * N_W) / 256 * 2, 256, 0, stream>>>(
            (const unsigned*)pf, cs, partial0, partial1);
        fan_reduce_kernel<<<(N_B * N_H * N_W) / 4 / 256, 256, 0, stream>>>(
            (const float4*)partial0, (const float4*)partial1, (float4*)out);
    } else {
        fan_backproject_kernel<1><<<(N_H * N_W) / 256, 256, 0, stream>>>(
            (const unsigned*)pf, cs, out, out);
    }
}

// Round 4
// 757.247 us; speedup vs baseline: 1.6776x; 1.5717x over previous
//
#include <hip/hip_runtime.h>
#include <hip/hip_fp16.h>
#include <math.h>

#define N_B 16
#define N_A 1024
#define N_D 1024
#define N_H 512
#define N_W 512

typedef _Float16 half2t __attribute__((ext_vector_type(2)));

__device__ inline half2t h2cast(unsigned u) {
    union { unsigned u; half2t h; } cv; cv.u = u; return cv.h;
}

__device__ inline float fdot2f(half2t a, half2t b, float c) {
#if __has_builtin(__builtin_amdgcn_fdot2)
    return __builtin_amdgcn_fdot2(a, b, c, false);
#else
    asm("v_dot2_f32_f16 %0, %1, %2, %0" : "+v"(c) : "v"(a), "v"(b));
    return c;
#endif
}

__device__ inline half2t pack_h2(float lo, float hi) {
#if __has_builtin(__builtin_amdgcn_cvt_pkrtz)
    auto r = __builtin_amdgcn_cvt_pkrtz(lo, hi);
    union { decltype(r) a; half2t h; } cv; cv.a = r; return cv.h;
#else
    half2t r; r.x = (_Float16)lo; r.y = (_Float16)hi; return r;
#endif
}

__device__ inline unsigned pack_u(float lo, float hi) {
    union { half2t h; unsigned u; } cv; cv.h = pack_h2(lo, hi); return cv.u;
}

// ---------------------------------------------------------------------------
// Setup: twiddle table W[k] = exp(-2*pi*i*k/1024), k<512 (double precision),
// and per-angle (cos, sin) table (double precision).
// ---------------------------------------------------------------------------
__global__ void fan_setup_kernel(const float* __restrict__ angles,
                                 float* __restrict__ twr,
                                 float* __restrict__ twi,
                                 float2* __restrict__ cs) {
    int t = blockIdx.x * 256 + threadIdx.x;
    if (t < 512) {
        double ang = -2.0 * M_PI * (double)t / 1024.0;
        twr[t] = (float)cos(ang);
        twi[t] = (float)sin(ang);
    }
    if (t < 1024) {
        double b = (double)angles[t];
        cs[t] = make_float2((float)cos(b), (float)sin(b));
    }
}

// ---------------------------------------------------------------------------
// FFT ramp filter, 4 batch-rows per block (one angle), as TWO packed complex
// FFTs: z0 = f[4g+0] + i f[4g+1], z1 = f[4g+2] + i f[4g+3]. Real filter
// commutes with the packing. Output entry pf4[((g*1024+a)*1024)+d] (16B):
//   { h2(b0[d],b0[d+1]), h2(b1[d],b1[d+1]), h2(b2[d],b2[d+1]), h2(b3[d],b3[d+1]) }
// so backprojection fetches 4 batches' bilinear pair with ONE dwordx4.
// ---------------------------------------------------------------------------
__global__ __launch_bounds__(256) void fan_fft_filter4_kernel(
    const float* __restrict__ sino, const float* __restrict__ filt,
    const float* __restrict__ twr_g, const float* __restrict__ twi_g,
    uint4* __restrict__ pf4) {
    __shared__ float s_re0[1024], s_im0[1024];
    __shared__ float s_re1[1024], s_im1[1024];
    __shared__ float s_twr[512], s_twi[512];

    const int tid = threadIdx.x;
    const int a = blockIdx.x & (N_A - 1);
    const int g = blockIdx.x >> 10;

    {
        float2 t0 = ((const float2*)twr_g)[tid];
        s_twr[2 * tid] = t0.x; s_twr[2 * tid + 1] = t0.y;
        float2 t1 = ((const float2*)twi_g)[tid];
        s_twi[2 * tid] = t1.x; s_twi[2 * tid + 1] = t1.y;
    }
    {
        const size_t rowstride = (size_t)N_A * N_D;
        const float* rb = sino + (size_t)(4 * g) * rowstride + (size_t)a * N_D;
        ((float4*)s_re0)[tid] = ((const float4*)(rb + 0 * rowstride))[tid];
        ((float4*)s_im0)[tid] = ((const float4*)(rb + 1 * rowstride))[tid];
        ((float4*)s_re1)[tid] = ((const float4*)(rb + 2 * rowstride))[tid];
        ((float4*)s_im1)[tid] = ((const float4*)(rb + 3 * rowstride))[tid];
    }
    __syncthreads();

    // ---- forward DIF: natural in -> bit-reversed out (both FFTs) ----
    for (int L = 9; L >= 0; --L) {
        const int half = 1 << L;
#pragma unroll
        for (int q = 0; q < 4; ++q) {
            // q=0,1 -> FFT0; q=2,3 -> FFT1 (compile-time select)
            float* re = (q < 2) ? s_re0 : s_re1;
            float* im = (q < 2) ? s_im0 : s_im1;
            const int bf = tid + ((q & 1) << 8);
            const int j = bf & (half - 1);
            const int blk = bf >> L;
            const int base = (blk << (L + 1)) + j;
            const int tw = j << (9 - L);
            const float wr = s_twr[tw], wi = s_twi[tw];
            const float ar = re[base], ai = im[base];
            const float br = re[base + half], bi = im[base + half];
            re[base] = ar + br;
            im[base] = ai + bi;
            const float dr = ar - br, di = ai - bi;
            re[base + half] = dr * wr - di * wi;
            im[base + half] = dr * wi + di * wr;
        }
        __syncthreads();
    }

    // ---- multiply by real ramp filter (bit-reversed order) ----
#pragma unroll
    for (int q = 0; q < 4; ++q) {
        const int i = tid + (q << 8);
        const int ri = (int)(__brev((unsigned)i) >> 22);
        const float f = filt[ri];
        s_re0[i] *= f; s_im0[i] *= f;
        s_re1[i] *= f; s_im1[i] *= f;
    }
    __syncthreads();

    // ---- inverse DIT: bit-reversed in -> natural out (unnormalized) ----
    for (int L = 0; L <= 9; ++L) {
        const int half = 1 << L;
#pragma unroll
        for (int q = 0; q < 4; ++q) {
            float* re = (q < 2) ? s_re0 : s_re1;
            float* im = (q < 2) ? s_im0 : s_im1;
            const int bf = tid + ((q & 1) << 8);
            const int j = bf & (half - 1);
            const int blk = bf >> L;
            const int base = (blk << (L + 1)) + j;
            const int tw = j << (9 - L);
            const float wr = s_twr[tw], wi = -s_twi[tw];
            const float ar = re[base], ai = im[base];
            const float tr = re[base + half], ti = im[base + half];
            const float br = tr * wr - ti * wi;
            const float bi = tr * wi + ti * wr;
            re[base] = ar + br;
            im[base] = ai + bi;
            re[base + half] = ar - br;
            im[base + half] = ai - bi;
        }
        __syncthreads();
    }

    // ---- scale by 1/N, emit 16B 4-batch pair entries ----
    const float invN = 1.0f / 1024.0f;
    uint4* dst = pf4 + ((size_t)g * N_A + (size_t)a) * N_D;
#pragma unroll
    for (int q = 0; q < 4; ++q) {
        const int n = tid + (q << 8);
        const int n1 = (n < 1023) ? n + 1 : n;  // pair partner (dup at edge)
        const float e = (n < 1023) ? 1.0f : 0.0f;
        uint4 v;
        v.x = pack_u(s_re0[n] * invN, s_re0[n1] * invN * e);
        v.y = pack_u(s_im0[n] * invN, s_im0[n1] * invN * e);
        v.z = pack_u(s_re1[n] * invN, s_re1[n1] * invN * e);
        v.w = pack_u(s_im1[n] * invN, s_im1[n1] * invN * e);
        dst[n] = v;
    }
}

// ---------------------------------------------------------------------------
// Backprojection: thread per pixel, 16 batch accumulators, angle loop with
// 1-deep software pipeline. Per angle: 4x global_load_dwordx4 (one per
// 4-batch group, SGPR base + shared voffset) + 16x v_dot2_f32_f16.
// SPLIT=2: blockIdx parity selects angle half; partials reduced after.
// ---------------------------------------------------------------------------
template <int SPLIT>
__global__ __launch_bounds__(256) void fan_backproject_kernel(
    const uint4* __restrict__ pf4, const float2* __restrict__ cs_g,
    float* __restrict__ dst0, float* __restrict__ dst1) {
    __shared__ float2 lcs[N_A];
    const int tid = threadIdx.x;
#pragma unroll
    for (int q = 0; q < 4; ++q) {
        const int a = tid + (q << 8);
        lcs[a] = cs_g[a];
    }
    __syncthreads();

    const int part = (SPLIT == 2) ? (blockIdx.x & 1) : 0;
    const int pb = (SPLIT == 2) ? (blockIdx.x >> 1) : blockIdx.x;
    const int ACNT = N_A / SPLIT;
    const int abase = part * ACNT;

    const int p = pb * 256 + tid;
    const int xi = p & (N_W - 1);
    const int yi = p >> 9;
    const float x = ((float)xi - 255.5f);  // VX = 1.0
    const float y = ((float)yi - 255.5f);

    const uint4* b0 = pf4;
    const uint4* b1 = pf4 + ((size_t)1 << 20);
    const uint4* b2 = pf4 + ((size_t)2 << 20);
    const uint4* b3 = pf4 + ((size_t)3 << 20);

    float acc[N_B];
#pragma unroll
    for (int b = 0; b < N_B; ++b) acc[b] = 0.0f;

    // geometry for one angle -> (voffset entry index, packed weights)
    auto geom = [&](int a, unsigned& off, half2t& wp) {
        const float2 csp = lcs[a];
        const float c = csp.x, s = csp.y;
        const float t = fmaf(x, c, fmaf(y, s, 750.0f));  // D_SI + X c + Y s
        float r = __builtin_amdgcn_rcpf(t);
        r = r * (2.0f - t * r);                          // 1 Newton step
        const float num = fmaf(y, c, -(x * s));
        const float idx = fmaf(num * r, 960.0f, 511.5f); // D_SD/DU = 960
        float i0f = floorf(idx);
        i0f = fminf(fmaxf(i0f, 0.0f), 1022.0f);
        const float frac = fminf(fmaxf(idx - i0f, 0.0f), 1.0f);
        float wd = 750.0f * r;
        wd = wd * wd;                                    // (D_SI/t)^2
        wd = (idx >= 0.0f && idx <= 1023.0f) ? wd : 0.0f;
        const float w1 = wd * frac;
        const float w0 = wd - w1;
        wp = pack_h2(w0, w1);
        off = ((unsigned)a << 10) + (unsigned)(int)i0f;
    };

    unsigned off;
    half2t wp;
    geom(abase, off, wp);
    uint4 v0 = b0[off], v1 = b1[off], v2 = b2[off], v3 = b3[off];

    for (int aa = 1; aa < ACNT; ++aa) {
        unsigned offn;
        half2t wpn;
        geom(abase + aa, offn, wpn);
        uint4 n0 = b0[offn], n1 = b1[offn], n2 = b2[offn], n3 = b3[offn];

        acc[0] = fdot2f(h2cast(v0.x), wp, acc[0]);
        acc[1] = fdot2f(h2cast(v0.y), wp, acc[1]);
        acc[2] = fdot2f(h2cast(v0.z), wp, acc[2]);
        acc[3] = fdot2f(h2cast(v0.w), wp, acc[3]);
        acc[4] = fdot2f(h2cast(v1.x), wp, acc[4]);
        acc[5] = fdot2f(h2cast(v1.y), wp, acc[5]);
        acc[6] = fdot2f(h2cast(v1.z), wp, acc[6]);
        acc[7] = fdot2f(h2cast(v1.w), wp, acc[7]);
        acc[8] = fdot2f(h2cast(v2.x), wp, acc[8]);
        acc[9] = fdot2f(h2cast(v2.y), wp, acc[9]);
        acc[10] = fdot2f(h2cast(v2.z), wp, acc[10]);
        acc[11] = fdot2f(h2cast(v2.w), wp, acc[11]);
        acc[12] = fdot2f(h2cast(v3.x), wp, acc[12]);
        acc[13] = fdot2f(h2cast(v3.y), wp, acc[13]);
        acc[14] = fdot2f(h2cast(v3.z), wp, acc[14]);
        acc[15] = fdot2f(h2cast(v3.w), wp, acc[15]);

        v0 = n0; v1 = n1; v2 = n2; v3 = n3; wp = wpn;
    }
    acc[0] = fdot2f(h2cast(v0.x), wp, acc[0]);
    acc[1] = fdot2f(h2cast(v0.y), wp, acc[1]);
    acc[2] = fdot2f(h2cast(v0.z), wp, acc[2]);
    acc[3] = fdot2f(h2cast(v0.w), wp, acc[3]);
    acc[4] = fdot2f(h2cast(v1.x), wp, acc[4]);
    acc[5] = fdot2f(h2cast(v1.y), wp, acc[5]);
    acc[6] = fdot2f(h2cast(v1.z), wp, acc[6]);
    acc[7] = fdot2f(h2cast(v1.w), wp, acc[7]);
    acc[8] = fdot2f(h2cast(v2.x), wp, acc[8]);
    acc[9] = fdot2f(h2cast(v2.y), wp, acc[9]);
    acc[10] = fdot2f(h2cast(v2.z), wp, acc[10]);
    acc[11] = fdot2f(h2cast(v2.w), wp, acc[11]);
    acc[12] = fdot2f(h2cast(v3.x), wp, acc[12]);
    acc[13] = fdot2f(h2cast(v3.y), wp, acc[13]);
    acc[14] = fdot2f(h2cast(v3.z), wp, acc[14]);
    acc[15] = fdot2f(h2cast(v3.w), wp, acc[15]);

    const float scale = 3.14159265358979323846f / 1024.0f;  // pi / A
    float* dst = (SPLIT == 2 && part == 1) ? dst1 : dst0;
#pragma unroll
    for (int b = 0; b < N_B; ++b) {
        dst[(size_t)b * (N_H * N_W) + (size_t)p] = acc[b] * scale;
    }
}

// ---------------------------------------------------------------------------
__global__ __launch_bounds__(256) void fan_reduce_kernel(
    const float4* __restrict__ a, const float4* __restrict__ b,
    float4* __restrict__ o) {
    const int i = blockIdx.x * 256 + threadIdx.x;
    const float4 va = a[i], vb = b[i];
    o[i] = make_float4(va.x + vb.x, va.y + vb.y, va.z + vb.z, va.w + vb.w);
}

// ---------------------------------------------------------------------------
extern "C" void kernel_launch(void* const* d_in, const int* in_sizes, int n_in,
                              void* d_out, int out_size, void* d_ws, size_t ws_size,
                              hipStream_t stream) {
    const float* sino = (const float*)d_in[0];    // [16, 1024, 1024] f32
    const float* filt = (const float*)d_in[1];    // [1024] f32
    const float* angles = (const float*)d_in[2];  // [1024] f32
    float* out = (float*)d_out;                   // [16, 512, 512] f32

    // ws layout: twr[512]f | twi[512]f | cs[1024]f2 | pad to 16KB |
    //            pf4 (64MB, [4][1024][1024] x 16B) | partial0/1 (16MB each)
    float* twr = (float*)d_ws;
    float* twi = twr + 512;
    float2* cs = (float2*)(twi + 512);
    char* base = (char*)d_ws;
    uint4* pf4 = (uint4*)(base + 16384);
    const size_t PF_BYTES = (size_t)4 * N_A * N_D * 16;  // 64 MB
    float* partial0 = (float*)(base + 16384 + PF_BYTES);
    float* partial1 = partial0 + (size_t)N_B * N_H * N_W;
    const size_t need = 16384 + PF_BYTES + 2 * (size_t)N_B * N_H * N_W * 4;

    fan_setup_kernel<<<4, 256, 0, stream>>>(angles, twr, twi, cs);
    fan_fft_filter4_kernel<<<4 * N_A, 256, 0, stream>>>(sino, filt, twr, twi,
                                                        pf4);
    if (ws_size >= need) {
        fan_backproject_kernel<2><<<(N_H * N_W) / 256 * 2, 256, 0, stream>>>(
            pf4, cs, partial0, partial1);
        fan_reduce_kernel<<<(N_B * N_H * N_W) / 4 / 256, 256, 0, stream>>>(
            (const float4*)partial0, (const float4*)partial1, (float4*)out);
    } else {
        fan_backproject_kernel<1><<<(N_H * N_W) / 256, 256, 0, stream>>>(
            pf4, cs, out, out);
    }
}

// Round 5
// 675.855 us; speedup vs baseline: 1.8797x; 1.1204x over previous
//
#include <hip/hip_runtime.h>
#include <hip/hip_fp16.h>
#include <math.h>

#define N_B 16
#define N_A 1024
#define N_D 1024
#define N_H 512
#define N_W 512

typedef _Float16 half2t __attribute__((ext_vector_type(2)));

__device__ inline half2t h2cast(unsigned u) {
    union { unsigned u; half2t h; } cv; cv.u = u; return cv.h;
}

__device__ inline float fdot2f(half2t a, half2t b, float c) {
#if __has_builtin(__builtin_amdgcn_fdot2)
    return __builtin_amdgcn_fdot2(a, b, c, false);
#else
    asm("v_dot2_f32_f16 %0, %1, %2, %0" : "+v"(c) : "v"(a), "v"(b));
    return c;
#endif
}

__device__ inline half2t pack_h2(float lo, float hi) {
#if __has_builtin(__builtin_amdgcn_cvt_pkrtz)
    auto r = __builtin_amdgcn_cvt_pkrtz(lo, hi);
    union { decltype(r) a; half2t h; } cv; cv.a = r; return cv.h;
#else
    half2t r; r.x = (_Float16)lo; r.y = (_Float16)hi; return r;
#endif
}

__device__ inline unsigned pack_u(float lo, float hi) {
    union { half2t h; unsigned u; } cv; cv.h = pack_h2(lo, hi); return cv.u;
}

__device__ inline float med3f(float a, float lo, float hi) {
#if __has_builtin(__builtin_amdgcn_fmed3f)
    return __builtin_amdgcn_fmed3f(a, lo, hi);
#else
    return fminf(fmaxf(a, lo), hi);
#endif
}

// ---------------------------------------------------------------------------
__global__ void fan_setup_kernel(const float* __restrict__ angles,
                                 float* __restrict__ twr,
                                 float* __restrict__ twi,
                                 float2* __restrict__ cs) {
    int t = blockIdx.x * 256 + threadIdx.x;
    if (t < 512) {
        double ang = -2.0 * M_PI * (double)t / 1024.0;
        twr[t] = (float)cos(ang);
        twi[t] = (float)sin(ang);
    }
    if (t < 1024) {
        double b = (double)angles[t];
        cs[t] = make_float2((float)cos(b), (float)sin(b));
    }
}

// ---------------------------------------------------------------------------
// FFT ramp filter, 4 batch-rows per block (one angle), as TWO packed complex
// FFTs. Output entry pf4[((g*1024+a)*1024)+d] (16B) = 4 batches' bilinear
// half2 pair (f[d], f[d+1]) so backprojection fetches with ONE dwordx4.
// ---------------------------------------------------------------------------
__global__ __launch_bounds__(256) void fan_fft_filter4_kernel(
    const float* __restrict__ sino, const float* __restrict__ filt,
    const float* __restrict__ twr_g, const float* __restrict__ twi_g,
    uint4* __restrict__ pf4) {
    __shared__ float s_re0[1024], s_im0[1024];
    __shared__ float s_re1[1024], s_im1[1024];
    __shared__ float s_twr[512], s_twi[512];

    const int tid = threadIdx.x;
    const int a = blockIdx.x & (N_A - 1);
    const int g = blockIdx.x >> 10;

    {
        float2 t0 = ((const float2*)twr_g)[tid];
        s_twr[2 * tid] = t0.x; s_twr[2 * tid + 1] = t0.y;
        float2 t1 = ((const float2*)twi_g)[tid];
        s_twi[2 * tid] = t1.x; s_twi[2 * tid + 1] = t1.y;
    }
    {
        const size_t rowstride = (size_t)N_A * N_D;
        const float* rb = sino + (size_t)(4 * g) * rowstride + (size_t)a * N_D;
        ((float4*)s_re0)[tid] = ((const float4*)(rb + 0 * rowstride))[tid];
        ((float4*)s_im0)[tid] = ((const float4*)(rb + 1 * rowstride))[tid];
        ((float4*)s_re1)[tid] = ((const float4*)(rb + 2 * rowstride))[tid];
        ((float4*)s_im1)[tid] = ((const float4*)(rb + 3 * rowstride))[tid];
    }
    __syncthreads();

    for (int L = 9; L >= 0; --L) {
        const int half = 1 << L;
#pragma unroll
        for (int q = 0; q < 4; ++q) {
            float* re = (q < 2) ? s_re0 : s_re1;
            float* im = (q < 2) ? s_im0 : s_im1;
            const int bf = tid + ((q & 1) << 8);
            const int j = bf & (half - 1);
            const int blk = bf >> L;
            const int base = (blk << (L + 1)) + j;
            const int tw = j << (9 - L);
            const float wr = s_twr[tw], wi = s_twi[tw];
            const float ar = re[base], ai = im[base];
            const float br = re[base + half], bi = im[base + half];
            re[base] = ar + br;
            im[base] = ai + bi;
            const float dr = ar - br, di = ai - bi;
            re[base + half] = dr * wr - di * wi;
            im[base + half] = dr * wi + di * wr;
        }
        __syncthreads();
    }

#pragma unroll
    for (int q = 0; q < 4; ++q) {
        const int i = tid + (q << 8);
        const int ri = (int)(__brev((unsigned)i) >> 22);
        const float f = filt[ri];
        s_re0[i] *= f; s_im0[i] *= f;
        s_re1[i] *= f; s_im1[i] *= f;
    }
    __syncthreads();

    for (int L = 0; L <= 9; ++L) {
        const int half = 1 << L;
#pragma unroll
        for (int q = 0; q < 4; ++q) {
            float* re = (q < 2) ? s_re0 : s_re1;
            float* im = (q < 2) ? s_im0 : s_im1;
            const int bf = tid + ((q & 1) << 8);
            const int j = bf & (half - 1);
            const int blk = bf >> L;
            const int base = (blk << (L + 1)) + j;
            const int tw = j << (9 - L);
            const float wr = s_twr[tw], wi = -s_twi[tw];
            const float ar = re[base], ai = im[base];
            const float tr = re[base + half], ti = im[base + half];
            const float br = tr * wr - ti * wi;
            const float bi = tr * wi + ti * wr;
            re[base] = ar + br;
            im[base] = ai + bi;
            re[base + half] = ar - br;
            im[base + half] = ai - bi;
        }
        __syncthreads();
    }

    const float invN = 1.0f / 1024.0f;
    uint4* dst = pf4 + ((size_t)g * N_A + (size_t)a) * N_D;
#pragma unroll
    for (int q = 0; q < 4; ++q) {
        const int n = tid + (q << 8);
        const int n1 = (n < 1023) ? n + 1 : n;
        const float e = (n < 1023) ? 1.0f : 0.0f;
        uint4 v;
        v.x = pack_u(s_re0[n] * invN, s_re0[n1] * invN * e);
        v.y = pack_u(s_im0[n] * invN, s_im0[n1] * invN * e);
        v.z = pack_u(s_re1[n] * invN, s_re1[n1] * invN * e);
        v.w = pack_u(s_im1[n] * invN, s_im1[n1] * invN * e);
        dst[n] = v;
    }
}

// ---------------------------------------------------------------------------
// Backprojection: 16x16 pixel tile per block (wave footprint 16x4 -> gather
// span ~32 detector entries ~5 cache lines/instr). 2-stage unroll, 4x
// dwordx4 gather + 16x v_dot2 per angle. SPLIT=2 on angle halves.
// ---------------------------------------------------------------------------
#define GEOMLOAD(ANG, WP, BOFF, V0, V1, V2, V3)                               \
    {                                                                         \
        const int a_ = (ANG);                                                 \
        const float2 csp = lcs[a_];                                           \
        const float c = csp.x, s = csp.y;                                     \
        const float t = fmaf(x, c, fmaf(y, s, 750.0f));                       \
        const float r = __builtin_amdgcn_rcpf(t);                             \
        const float num = fmaf(y, c, -(x * s));                               \
        const float idx = fmaf(num * r, 960.0f, 511.5f);                      \
        const float idxc = med3f(idx, 0.0f, 1023.0f);                         \
        const float i0f = floorf(idxc);                                       \
        const float frac = idxc - i0f;                                        \
        float wr = 750.0f * r;                                                \
        float wd = wr * wr;                                                   \
        wd = (idx == idxc) ? wd : 0.0f;                                       \
        const float w1 = wd * frac;                                           \
        const float w0 = wd - w1;                                             \
        WP = pack_h2(w0, w1);                                                 \
        BOFF = ((unsigned)a_ << 14) + ((unsigned)(int)i0f << 4);              \
        V0 = *(const uint4*)(base0 + BOFF);                                   \
        V1 = *(const uint4*)(base1 + BOFF);                                   \
        V2 = *(const uint4*)(base2 + BOFF);                                   \
        V3 = *(const uint4*)(base3 + BOFF);                                   \
    }

#define CONSUME(WP, V0, V1, V2, V3)                                           \
    {                                                                         \
        acc[0] = fdot2f(h2cast(V0.x), WP, acc[0]);                            \
        acc[1] = fdot2f(h2cast(V0.y), WP, acc[1]);                            \
        acc[2] = fdot2f(h2cast(V0.z), WP, acc[2]);                            \
        acc[3] = fdot2f(h2cast(V0.w), WP, acc[3]);                            \
        acc[4] = fdot2f(h2cast(V1.x), WP, acc[4]);                            \
        acc[5] = fdot2f(h2cast(V1.y), WP, acc[5]);                            \
        acc[6] = fdot2f(h2cast(V1.z), WP, acc[6]);                            \
        acc[7] = fdot2f(h2cast(V1.w), WP, acc[7]);                            \
        acc[8] = fdot2f(h2cast(V2.x), WP, acc[8]);                            \
        acc[9] = fdot2f(h2cast(V2.y), WP, acc[9]);                            \
        acc[10] = fdot2f(h2cast(V2.z), WP, acc[10]);                          \
        acc[11] = fdot2f(h2cast(V2.w), WP, acc[11]);                          \
        acc[12] = fdot2f(h2cast(V3.x), WP, acc[12]);                          \
        acc[13] = fdot2f(h2cast(V3.y), WP, acc[13]);                          \
        acc[14] = fdot2f(h2cast(V3.z), WP, acc[14]);                          \
        acc[15] = fdot2f(h2cast(V3.w), WP, acc[15]);                          \
    }

template <int SPLIT>
__global__ __launch_bounds__(256) void fan_backproject_kernel(
    const uint4* __restrict__ pf4, const float2* __restrict__ cs_g,
    float* __restrict__ dst0, float* __restrict__ dst1) {
    __shared__ float2 lcs[N_A];
    const int tid = threadIdx.x;
#pragma unroll
    for (int q = 0; q < 4; ++q) {
        const int a = tid + (q << 8);
        lcs[a] = cs_g[a];
    }
    __syncthreads();

    const int part = (SPLIT == 2) ? (blockIdx.x & 1) : 0;
    const int tb = (SPLIT == 2) ? (blockIdx.x >> 1) : blockIdx.x;
    const int ACNT = N_A / SPLIT;
    const int abase = part * ACNT;

    // 16x16 tile: 32x32 grid of tiles
    const int tile_x = tb & 31;
    const int tile_y = tb >> 5;
    const int tx = tid & 15;
    const int ty = tid >> 4;
    const int xi = tile_x * 16 + tx;
    const int yi = tile_y * 16 + ty;
    const float x = ((float)xi - 255.5f);  // VX = 1.0
    const float y = ((float)yi - 255.5f);

    const char* base0 = (const char*)pf4;
    const char* base1 = base0 + ((size_t)1 << 24);
    const char* base2 = base0 + ((size_t)2 << 24);
    const char* base3 = base0 + ((size_t)3 << 24);

    float acc[N_B];
#pragma unroll
    for (int b = 0; b < N_B; ++b) acc[b] = 0.0f;

    unsigned boffA, boffB;
    half2t wpA, wpB;
    uint4 A0, A1, A2, A3, B0, B1, B2, B3;

    GEOMLOAD(abase, wpA, boffA, A0, A1, A2, A3);
    for (int aa = 1; aa + 1 < ACNT; aa += 2) {
        GEOMLOAD(abase + aa, wpB, boffB, B0, B1, B2, B3);
        CONSUME(wpA, A0, A1, A2, A3);
        GEOMLOAD(abase + aa + 1, wpA, boffA, A0, A1, A2, A3);
        CONSUME(wpB, B0, B1, B2, B3);
    }
    GEOMLOAD(abase + ACNT - 1, wpB, boffB, B0, B1, B2, B3);
    CONSUME(wpA, A0, A1, A2, A3);
    CONSUME(wpB, B0, B1, B2, B3);

    const float scale = 3.14159265358979323846f / 1024.0f;  // pi / A
    float* dst = (SPLIT == 2 && part == 1) ? dst1 : dst0;
    const size_t pix = (size_t)yi * N_W + (size_t)xi;
#pragma unroll
    for (int b = 0; b < N_B; ++b) {
        dst[(size_t)b * (N_H * N_W) + pix] = acc[b] * scale;
    }
}

// ---------------------------------------------------------------------------
__global__ __launch_bounds__(256) void fan_reduce_kernel(
    const float4* __restrict__ a, const float4* __restrict__ b,
    float4* __restrict__ o) {
    const int i = blockIdx.x * 256 + threadIdx.x;
    const float4 va = a[i], vb = b[i];
    o[i] = make_float4(va.x + vb.x, va.y + vb.y, va.z + vb.z, va.w + vb.w);
}

// ---------------------------------------------------------------------------
extern "C" void kernel_launch(void* const* d_in, const int* in_sizes, int n_in,
                              void* d_out, int out_size, void* d_ws, size_t ws_size,
                              hipStream_t stream) {
    const float* sino = (const float*)d_in[0];    // [16, 1024, 1024] f32
    const float* filt = (const float*)d_in[1];    // [1024] f32
    const float* angles = (const float*)d_in[2];  // [1024] f32
    float* out = (float*)d_out;                   // [16, 512, 512] f32

    float* twr = (float*)d_ws;
    float* twi = twr + 512;
    float2* cs = (float2*)(twi + 512);
    char* base = (char*)d_ws;
    uint4* pf4 = (uint4*)(base + 16384);
    const size_t PF_BYTES = (size_t)4 * N_A * N_D * 16;  // 64 MB
    float* partial0 = (float*)(base + 16384 + PF_BYTES);
    float* partial1 = partial0 + (size_t)N_B * N_H * N_W;
    const size_t need = 16384 + PF_BYTES + 2 * (size_t)N_B * N_H * N_W * 4;

    fan_setup_kernel<<<4, 256, 0, stream>>>(angles, twr, twi, cs);
    fan_fft_filter4_kernel<<<4 * N_A, 256, 0, stream>>>(sino, filt, twr, twi,
                                                        pf4);
    if (ws_size >= need) {
        fan_backproject_kernel<2><<<(N_H * N_W) / 256 * 2, 256, 0, stream>>>(
            pf4, cs, partial0, partial1);
        fan_reduce_kernel<<<(N_B * N_H * N_W) / 4 / 256, 256, 0, stream>>>(
            (const float4*)partial0, (const float4*)partial1, (float4*)out);
    } else {
        fan_backproject_kernel<1><<<(N_H * N_W) / 256, 256, 0, stream>>>(
            pf4, cs, out, out);
    }
}

// Round 6
// 609.189 us; speedup vs baseline: 2.0854x; 1.1094x over previous
//
#include <hip/hip_runtime.h>
#include <hip/hip_fp16.h>
#include <math.h>

#define N_B 16
#define N_A 1024
#define N_D 1024
#define N_H 512
#define N_W 512

typedef _Float16 half2t __attribute__((ext_vector_type(2)));

__device__ inline half2t h2cast(unsigned u) {
    union { unsigned u; half2t h; } cv; cv.u = u; return cv.h;
}

__device__ inline float fdot2f(half2t a, half2t b, float c) {
#if __has_builtin(__builtin_amdgcn_fdot2)
    return __builtin_amdgcn_fdot2(a, b, c, false);
#else
    asm("v_dot2_f32_f16 %0, %1, %2, %0" : "+v"(c) : "v"(a), "v"(b));
    return c;
#endif
}

__device__ inline half2t pack_h2(float lo, float hi) {
#if __has_builtin(__builtin_amdgcn_cvt_pkrtz)
    auto r = __builtin_amdgcn_cvt_pkrtz(lo, hi);
    union { decltype(r) a; half2t h; } cv; cv.a = r; return cv.h;
#else
    half2t r; r.x = (_Float16)lo; r.y = (_Float16)hi; return r;
#endif
}

__device__ inline unsigned pack_u(float lo, float hi) {
    union { half2t h; unsigned u; } cv; cv.h = pack_h2(lo, hi); return cv.u;
}

__device__ inline float med3f(float a, float lo, float hi) {
#if __has_builtin(__builtin_amdgcn_fmed3f)
    return __builtin_amdgcn_fmed3f(a, lo, hi);
#else
    return fminf(fmaxf(a, lo), hi);
#endif
}

#define SB() __builtin_amdgcn_sched_barrier(0)

// ---------------------------------------------------------------------------
__global__ void fan_setup_kernel(const float* __restrict__ angles,
                                 float* __restrict__ twr,
                                 float* __restrict__ twi,
                                 float2* __restrict__ cs) {
    int t = blockIdx.x * 256 + threadIdx.x;
    if (t < 512) {
        double ang = -2.0 * M_PI * (double)t / 1024.0;
        twr[t] = (float)cos(ang);
        twi[t] = (float)sin(ang);
    }
    if (t < 1024) {
        double b = (double)angles[t];
        cs[t] = make_float2((float)cos(b), (float)sin(b));
    }
}

// ---------------------------------------------------------------------------
// FFT ramp filter, 4 batch-rows per block (one angle), as TWO packed complex
// FFTs. Output entry pf4[((g*1024+a)*1024)+d] (16B) = 4 batches' bilinear
// half2 pair (f[d], f[d+1]) so backprojection fetches with ONE dwordx4.
// ---------------------------------------------------------------------------
__global__ __launch_bounds__(256) void fan_fft_filter4_kernel(
    const float* __restrict__ sino, const float* __restrict__ filt,
    const float* __restrict__ twr_g, const float* __restrict__ twi_g,
    uint4* __restrict__ pf4) {
    __shared__ float s_re0[1024], s_im0[1024];
    __shared__ float s_re1[1024], s_im1[1024];
    __shared__ float s_twr[512], s_twi[512];

    const int tid = threadIdx.x;
    const int a = blockIdx.x & (N_A - 1);
    const int g = blockIdx.x >> 10;

    {
        float2 t0 = ((const float2*)twr_g)[tid];
        s_twr[2 * tid] = t0.x; s_twr[2 * tid + 1] = t0.y;
        float2 t1 = ((const float2*)twi_g)[tid];
        s_twi[2 * tid] = t1.x; s_twi[2 * tid + 1] = t1.y;
    }
    {
        const size_t rowstride = (size_t)N_A * N_D;
        const float* rb = sino + (size_t)(4 * g) * rowstride + (size_t)a * N_D;
        ((float4*)s_re0)[tid] = ((const float4*)(rb + 0 * rowstride))[tid];
        ((float4*)s_im0)[tid] = ((const float4*)(rb + 1 * rowstride))[tid];
        ((float4*)s_re1)[tid] = ((const float4*)(rb + 2 * rowstride))[tid];
        ((float4*)s_im1)[tid] = ((const float4*)(rb + 3 * rowstride))[tid];
    }
    __syncthreads();

    for (int L = 9; L >= 0; --L) {
        const int half = 1 << L;
#pragma unroll
        for (int q = 0; q < 4; ++q) {
            float* re = (q < 2) ? s_re0 : s_re1;
            float* im = (q < 2) ? s_im0 : s_im1;
            const int bf = tid + ((q & 1) << 8);
            const int j = bf & (half - 1);
            const int blk = bf >> L;
            const int base = (blk << (L + 1)) + j;
            const int tw = j << (9 - L);
            const float wr = s_twr[tw], wi = s_twi[tw];
            const float ar = re[base], ai = im[base];
            const float br = re[base + half], bi = im[base + half];
            re[base] = ar + br;
            im[base] = ai + bi;
            const float dr = ar - br, di = ai - bi;
            re[base + half] = dr * wr - di * wi;
            im[base + half] = dr * wi + di * wr;
        }
        __syncthreads();
    }

#pragma unroll
    for (int q = 0; q < 4; ++q) {
        const int i = tid + (q << 8);
        const int ri = (int)(__brev((unsigned)i) >> 22);
        const float f = filt[ri];
        s_re0[i] *= f; s_im0[i] *= f;
        s_re1[i] *= f; s_im1[i] *= f;
    }
    __syncthreads();

    for (int L = 0; L <= 9; ++L) {
        const int half = 1 << L;
#pragma unroll
        for (int q = 0; q < 4; ++q) {
            float* re = (q < 2) ? s_re0 : s_re1;
            float* im = (q < 2) ? s_im0 : s_im1;
            const int bf = tid + ((q & 1) << 8);
            const int j = bf & (half - 1);
            const int blk = bf >> L;
            const int base = (blk << (L + 1)) + j;
            const int tw = j << (9 - L);
            const float wr = s_twr[tw], wi = -s_twi[tw];
            const float ar = re[base], ai = im[base];
            const float tr = re[base + half], ti = im[base + half];
            const float br = tr * wr - ti * wi;
            const float bi = tr * wi + ti * wr;
            re[base] = ar + br;
            im[base] = ai + bi;
            re[base + half] = ar - br;
            im[base + half] = ai - bi;
        }
        __syncthreads();
    }

    const float invN = 1.0f / 1024.0f;
    uint4* dst = pf4 + ((size_t)g * N_A + (size_t)a) * N_D;
#pragma unroll
    for (int q = 0; q < 4; ++q) {
        const int n = tid + (q << 8);
        const int n1 = (n < 1023) ? n + 1 : n;
        const float e = (n < 1023) ? 1.0f : 0.0f;
        uint4 v;
        v.x = pack_u(s_re0[n] * invN, s_re0[n1] * invN * e);
        v.y = pack_u(s_im0[n] * invN, s_im0[n1] * invN * e);
        v.z = pack_u(s_re1[n] * invN, s_re1[n1] * invN * e);
        v.w = pack_u(s_im1[n] * invN, s_im1[n1] * invN * e);
        dst[n] = v;
    }
}

// ---------------------------------------------------------------------------
// Backprojection: 16x16 pixel tile per block; 4x saddr dwordx4 gather + 16x
// v_dot2 per angle; explicit 2-deep pipeline held open by sched_barrier(0);
// XCD-chunked block swizzle so same-XCD blocks are contiguous tiles.
// ---------------------------------------------------------------------------
#define CONSUME(WP, V0, V1, V2, V3)                                           \
    {                                                                         \
        acc[0] = fdot2f(h2cast(V0.x), WP, acc[0]);                            \
        acc[1] = fdot2f(h2cast(V0.y), WP, acc[1]);                            \
        acc[2] = fdot2f(h2cast(V0.z), WP, acc[2]);                            \
        acc[3] = fdot2f(h2cast(V0.w), WP, acc[3]);                            \
        acc[4] = fdot2f(h2cast(V1.x), WP, acc[4]);                            \
        acc[5] = fdot2f(h2cast(V1.y), WP, acc[5]);                            \
        acc[6] = fdot2f(h2cast(V1.z), WP, acc[6]);                            \
        acc[7] = fdot2f(h2cast(V1.w), WP, acc[7]);                            \
        acc[8] = fdot2f(h2cast(V2.x), WP, acc[8]);                            \
        acc[9] = fdot2f(h2cast(V2.y), WP, acc[9]);                            \
        acc[10] = fdot2f(h2cast(V2.z), WP, acc[10]);                          \
        acc[11] = fdot2f(h2cast(V2.w), WP, acc[11]);                          \
        acc[12] = fdot2f(h2cast(V3.x), WP, acc[12]);                          \
        acc[13] = fdot2f(h2cast(V3.y), WP, acc[13]);                          \
        acc[14] = fdot2f(h2cast(V3.z), WP, acc[14]);                          \
        acc[15] = fdot2f(h2cast(V3.w), WP, acc[15]);                          \
    }

template <int SPLIT>
__global__ __launch_bounds__(256) void fan_backproject_kernel(
    const uint4* __restrict__ pf4, const float2* __restrict__ cs_g,
    float* __restrict__ dst0, float* __restrict__ dst1) {
    __shared__ float2 lcs[N_A];
    const int tid = threadIdx.x;
#pragma unroll
    for (int q = 0; q < 4; ++q) {
        const int a = tid + (q << 8);
        lcs[a] = cs_g[a];
    }
    __syncthreads();

    // XCD-chunked bijective swizzle (gridDim.x % 8 == 0): consecutive ids on
    // one XCD become contiguous tiles of the same angle-part.
    const unsigned nwg = gridDim.x;
    const unsigned swz = (blockIdx.x & 7) * (nwg >> 3) + (blockIdx.x >> 3);
    const int part = (SPLIT >= 2) ? (int)(swz >> 10) : 0;
    const int tb = (SPLIT >= 2) ? (int)(swz & 1023) : (int)swz;
    const int ACNT = N_A / SPLIT;
    const int abase = part * ACNT;

    // 16x16 tile: 32x32 grid of tiles
    const int tile_x = tb & 31;
    const int tile_y = tb >> 5;
    const int tx = tid & 15;
    const int ty = tid >> 4;
    const int xi = tile_x * 16 + tx;
    const int yi = tile_y * 16 + ty;
    const float x = ((float)xi - 255.5f);  // VX = 1.0
    const float y = ((float)yi - 255.5f);

    // uniform per-group bases -> SGPR pairs; 32-bit element index -> saddr
    const uint4* __restrict__ g0 = pf4;
    const uint4* __restrict__ g1 = pf4 + ((size_t)1 << 20);
    const uint4* __restrict__ g2 = pf4 + ((size_t)2 << 20);
    const uint4* __restrict__ g3 = pf4 + ((size_t)3 << 20);

    float acc[N_B];
#pragma unroll
    for (int b = 0; b < N_B; ++b) acc[b] = 0.0f;

    half2t wpA, wpB;
    uint4 A0, A1, A2, A3, B0, B1, B2, B3;

    auto geomload = [&](int a_, half2t& wp, uint4& V0, uint4& V1, uint4& V2,
                        uint4& V3) {
        const float2 csp = lcs[a_];
        const float c = csp.x, s = csp.y;
        const float t = fmaf(x, c, fmaf(y, s, 750.0f));  // D_SI + X c + Y s
        const float r = __builtin_amdgcn_rcpf(t);
        const float num = fmaf(y, c, -(x * s));
        const float idx = fmaf(num * r, 960.0f, 511.5f); // D_SD/DU = 960
        const float idxc = med3f(idx, 0.0f, 1023.0f);
        const float i0f = floorf(idxc);
        const float frac = idxc - i0f;
        const float wr = 750.0f * r;
        float wd = wr * wr;                              // (D_SI/t)^2
        wd = (idx == idxc) ? wd : 0.0f;
        const float w1 = wd * frac;
        const float w0 = wd - w1;
        wp = pack_h2(w0, w1);
        const unsigned off = ((unsigned)a_ << 10) + (unsigned)(int)i0f;
        V0 = g0[off];
        V1 = g1[off];
        V2 = g2[off];
        V3 = g3[off];
    };

    geomload(abase, wpA, A0, A1, A2, A3);
    SB();
    for (int aa = 1; aa + 1 < ACNT; aa += 2) {
        geomload(abase + aa, wpB, B0, B1, B2, B3);
        SB();
        CONSUME(wpA, A0, A1, A2, A3);
        SB();
        geomload(abase + aa + 1, wpA, A0, A1, A2, A3);
        SB();
        CONSUME(wpB, B0, B1, B2, B3);
        SB();
    }
    geomload(abase + ACNT - 1, wpB, B0, B1, B2, B3);
    CONSUME(wpA, A0, A1, A2, A3);
    CONSUME(wpB, B0, B1, B2, B3);

    const float scale = 3.14159265358979323846f / 1024.0f;  // pi / A
    float* dst = (SPLIT >= 2 && part == 1) ? dst1 : dst0;
    const size_t pix = (size_t)yi * N_W + (size_t)xi;
#pragma unroll
    for (int b = 0; b < N_B; ++b) {
        dst[(size_t)b * (N_H * N_W) + pix] = acc[b] * scale;
    }
}

// ---------------------------------------------------------------------------
__global__ __launch_bounds__(256) void fan_reduce_kernel(
    const float4* __restrict__ a, const float4* __restrict__ b,
    float4* __restrict__ o) {
    const int i = blockIdx.x * 256 + threadIdx.x;
    const float4 va = a[i], vb = b[i];
    o[i] = make_float4(va.x + vb.x, va.y + vb.y, va.z + vb.z, va.w + vb.w);
}

// ---------------------------------------------------------------------------
extern "C" void kernel_launch(void* const* d_in, const int* in_sizes, int n_in,
                              void* d_out, int out_size, void* d_ws, size_t ws_size,
                              hipStream_t stream) {
    const float* sino = (const float*)d_in[0];    // [16, 1024, 1024] f32
    const float* filt = (const float*)d_in[1];    // [1024] f32
    const float* angles = (const float*)d_in[2];  // [1024] f32
    float* out = (float*)d_out;                   // [16, 512, 512] f32

    float* twr = (float*)d_ws;
    float* twi = twr + 512;
    float2* cs = (float2*)(twi + 512);
    char* base = (char*)d_ws;
    uint4* pf4 = (uint4*)(base + 16384);
    const size_t PF_BYTES = (size_t)4 * N_A * N_D * 16;  // 64 MB
    float* partial0 = (float*)(base + 16384 + PF_BYTES);
    float* partial1 = partial0 + (size_t)N_B * N_H * N_W;
    const size_t need = 16384 + PF_BYTES + 2 * (size_t)N_B * N_H * N_W * 4;

    fan_setup_kernel<<<4, 256, 0, stream>>>(angles, twr, twi, cs);
    fan_fft_filter4_kernel<<<4 * N_A, 256, 0, stream>>>(sino, filt, twr, twi,
                                                        pf4);
    if (ws_size >= need) {
        fan_backproject_kernel<2><<<(N_H * N_W) / 256 * 2, 256, 0, stream>>>(
            pf4, cs, partial0, partial1);
        fan_reduce_kernel<<<(N_B * N_H * N_W) / 4 / 256, 256, 0, stream>>>(
            (const float4*)partial0, (const float4*)partial1, (float4*)out);
    } else {
        fan_backproject_kernel<1><<<(N_H * N_W) / 256, 256, 0, stream>>>(
            pf4, cs, out, out);
    }
}